// Round 1
// baseline (955.820 us; speedup 1.0000x reference)
//
#include <hip/hip_runtime.h>

#define N_NODES_C 100000
#define N_EDGES_C 800000
#define FEATS 100
#define NCLS 50
#define GENE 20000

// ---------------------------------------------------------------------------
// Kernel 1: per-edge scale + degree count
// ---------------------------------------------------------------------------
__global__ void edge_prep_kernel(const int* __restrict__ node_ids,
                                 const int* __restrict__ src,
                                 const int* __restrict__ dst,
                                 const float* __restrict__ ew,
                                 const float* __restrict__ alpha,
                                 float* __restrict__ scale,
                                 float* __restrict__ deg) {
    int e = blockIdx.x * blockDim.x + threadIdx.x;
    if (e >= N_EDGES_C) return;
    int s = src[e];
    int d = dst[e];
    int sid = node_ids[s];
    int did = node_ids[d];
    int idx = GENE + 1;                       // default: cell-cell
    if (sid >= 0 && did < 0) idx = sid;       // gene -> cell
    else if (did >= 0 && sid < 0) idx = did;  // cell -> gene
    else if (sid >= 0 && did >= 0) idx = GENE;// gene -> gene
    scale[e] = alpha[idx] * ew[e];
    atomicAdd(&deg[d], 1.0f);
}

// ---------------------------------------------------------------------------
// Kernel 2: inverse degree (mean denominator); zero-degree -> 0
// ---------------------------------------------------------------------------
__global__ void inv_deg_kernel(const float* __restrict__ deg,
                               float* __restrict__ inv) {
    int n = blockIdx.x * blockDim.x + threadIdx.x;
    if (n >= N_NODES_C) return;
    float d = deg[n];
    inv[n] = (d > 0.0f) ? (1.0f / d) : 0.0f;
}

// ---------------------------------------------------------------------------
// Kernel 3: edge scatter  neigh[dst] += h[src] * scale
// 32 lanes per edge, 8 edges per 256-thread block.
// ---------------------------------------------------------------------------
__global__ void scatter_kernel(const float* __restrict__ h,
                               const float* __restrict__ scale,
                               const int* __restrict__ src,
                               const int* __restrict__ dst,
                               float* __restrict__ neigh) {
    int t = blockIdx.x * 256 + threadIdx.x;
    int e = t >> 5;
    int lane = t & 31;
    if (e >= N_EDGES_C) return;
    float sc = scale[e];
    const float* __restrict__ hr = h + (size_t)src[e] * FEATS;
    float* __restrict__ nr = neigh + (size_t)dst[e] * FEATS;
    #pragma unroll
    for (int f = lane; f < FEATS; f += 32) {
        atomicAdd(&nr[f], hr[f] * sc);
    }
}

// ---------------------------------------------------------------------------
// Kernel 4: dense layer  out[n][j] = act( (in[n]*s) . W[j] + b[j] )
// Thread j owns output column j; W row held in VGPRs; input rows staged in
// LDS and consumed as broadcast float4 reads. 8 nodes per barrier round.
// N_NODES_C % 8 == 0, so no tail guards needed.
// ---------------------------------------------------------------------------
template <int NOUT, bool RELU, bool SCALE_IN>
__global__ __launch_bounds__(128) void dense_kernel(
        const float* __restrict__ in,
        const float* __restrict__ inv,
        const float* __restrict__ W,
        const float* __restrict__ b,
        float* __restrict__ out) {
    __shared__ float rows[8][FEATS];
    const int j = threadIdx.x;

    float w[FEATS];
    float bias = 0.0f;
    if (j < NOUT) {
        bias = b[j];
        #pragma unroll
        for (int k4 = 0; k4 < FEATS / 4; ++k4) {
            float4 v = reinterpret_cast<const float4*>(W + (size_t)j * FEATS)[k4];
            w[4 * k4 + 0] = v.x;
            w[4 * k4 + 1] = v.y;
            w[4 * k4 + 2] = v.z;
            w[4 * k4 + 3] = v.w;
        }
    }

    const int ngroups = N_NODES_C / 8;
    for (int g = blockIdx.x; g < ngroups; g += gridDim.x) {
        const int n0 = g * 8;
        // Stage 8 rows (pre-scaled by inv_deg where requested)
        if (j < FEATS) {
            #pragma unroll
            for (int m = 0; m < 8; ++m) {
                int n = n0 + m;
                float s = SCALE_IN ? inv[n] : 1.0f;
                rows[m][j] = in[(size_t)n * FEATS + j] * s;
            }
        }
        __syncthreads();
        if (j < NOUT) {
            #pragma unroll
            for (int m = 0; m < 8; ++m) {
                float acc = bias;
                #pragma unroll
                for (int k4 = 0; k4 < FEATS / 4; ++k4) {
                    float4 r = reinterpret_cast<const float4*>(rows[m])[k4];
                    acc += r.x * w[4 * k4 + 0];
                    acc += r.y * w[4 * k4 + 1];
                    acc += r.z * w[4 * k4 + 2];
                    acc += r.w * w[4 * k4 + 3];
                }
                if (RELU) acc = fmaxf(acc, 0.0f);
                out[(size_t)(n0 + m) * NOUT + j] = acc;
            }
        }
        __syncthreads();
    }
}

// ---------------------------------------------------------------------------
extern "C" void kernel_launch(void* const* d_in, const int* in_sizes, int n_in,
                              void* d_out, int out_size, void* d_ws, size_t ws_size,
                              hipStream_t stream) {
    const float* features = (const float*)d_in[0];
    const int*   node_ids = (const int*)d_in[1];
    const int*   src      = (const int*)d_in[2];
    const int*   dst      = (const int*)d_in[3];
    const float* ew       = (const float*)d_in[4];
    const float* alpha    = (const float*)d_in[5];
    const float* W1       = (const float*)d_in[6];
    const float* b1       = (const float*)d_in[7];
    const float* W2       = (const float*)d_in[8];
    const float* b2       = (const float*)d_in[9];
    const float* lin_w    = (const float*)d_in[10];
    const float* lin_b    = (const float*)d_in[11];
    float* out = (float*)d_out;

    char* ws = (char*)d_ws;
    size_t off = 0;
    auto alloc = [&](size_t bytes) {
        void* p = ws + off;
        off += (bytes + 255) & ~(size_t)255;
        return p;
    };
    float* scale = (float*)alloc((size_t)N_EDGES_C * 4);
    float* deg   = (float*)alloc((size_t)N_NODES_C * 4);
    float* inv   = (float*)alloc((size_t)N_NODES_C * 4);
    float* neigh = (float*)alloc((size_t)N_NODES_C * FEATS * 4);
    float* h     = (float*)alloc((size_t)N_NODES_C * FEATS * 4);
    (void)ws_size;

    hipMemsetAsync(deg, 0, (size_t)N_NODES_C * 4, stream);
    hipMemsetAsync(neigh, 0, (size_t)N_NODES_C * FEATS * 4, stream);

    edge_prep_kernel<<<(N_EDGES_C + 255) / 256, 256, 0, stream>>>(
        node_ids, src, dst, ew, alpha, scale, deg);
    inv_deg_kernel<<<(N_NODES_C + 255) / 256, 256, 0, stream>>>(deg, inv);

    // Layer 1
    scatter_kernel<<<N_EDGES_C / 8, 256, 0, stream>>>(features, scale, src, dst, neigh);
    dense_kernel<FEATS, true, true><<<2048, 128, 0, stream>>>(neigh, inv, W1, b1, h);

    // Layer 2
    hipMemsetAsync(neigh, 0, (size_t)N_NODES_C * FEATS * 4, stream);
    scatter_kernel<<<N_EDGES_C / 8, 256, 0, stream>>>(h, scale, src, dst, neigh);
    dense_kernel<FEATS, true, true><<<2048, 128, 0, stream>>>(neigh, inv, W2, b2, h);

    // Classifier
    dense_kernel<NCLS, false, false><<<2048, 128, 0, stream>>>(h, nullptr, lin_w, lin_b, out);
}

// Round 2
// 399.371 us; speedup vs baseline: 2.3933x; 2.3933x over previous
//
#include <hip/hip_runtime.h>

#define N_NODES_C 100000
#define N_EDGES_C 800000
#define FEATS 100
#define NCLS 50
#define GENE 20000
#define SCAN_BLK 1024
#define SCAN_NBLK ((N_NODES_C + SCAN_BLK - 1) / SCAN_BLK)   // 98

// ---------------------------------------------------------------------------
// Degree count (int atomics — cheap, 800K increments into 400 KB table)
// ---------------------------------------------------------------------------
__global__ void deg_count_kernel(const int* __restrict__ dst,
                                 int* __restrict__ deg) {
    int e = blockIdx.x * blockDim.x + threadIdx.x;
    if (e >= N_EDGES_C) return;
    atomicAdd(&deg[dst[e]], 1);
}

// ---------------------------------------------------------------------------
// 3-kernel exclusive scan over deg[100000] -> row_ptr[100001]
// scan1: in-place inclusive scan per 1024-block + block totals
// ---------------------------------------------------------------------------
__global__ __launch_bounds__(1024) void scan1_kernel(int* __restrict__ deg,
                                                     int* __restrict__ bsum) {
    __shared__ int wsum[16];
    const int i = blockIdx.x * SCAN_BLK + threadIdx.x;
    const int lane = threadIdx.x & 63;
    const int wid = threadIdx.x >> 6;
    int v = (i < N_NODES_C) ? deg[i] : 0;
    #pragma unroll
    for (int d = 1; d < 64; d <<= 1) {
        int t = __shfl_up(v, d);
        if (lane >= d) v += t;
    }
    if (lane == 63) wsum[wid] = v;
    __syncthreads();
    if (wid == 0) {
        int s = (lane < 16) ? wsum[lane] : 0;
        #pragma unroll
        for (int d = 1; d < 16; d <<= 1) {
            int t = __shfl_up(s, d);
            if (lane >= d) s += t;
        }
        if (lane < 16) wsum[lane] = s;
    }
    __syncthreads();
    if (wid > 0) v += wsum[wid - 1];
    if (i < N_NODES_C) deg[i] = v;           // in-place inclusive scan
    if (threadIdx.x == SCAN_BLK - 1) bsum[blockIdx.x] = v;
}

__global__ void scan2_kernel(int* __restrict__ bsum) {
    __shared__ int tmp[SCAN_NBLK];
    if (threadIdx.x < SCAN_NBLK) tmp[threadIdx.x] = bsum[threadIdx.x];
    __syncthreads();
    if (threadIdx.x == 0) {
        int off = 0;
        for (int j = 0; j < SCAN_NBLK; ++j) { int t = tmp[j]; tmp[j] = off; off += t; }
    }
    __syncthreads();
    if (threadIdx.x < SCAN_NBLK) bsum[threadIdx.x] = tmp[threadIdx.x];
}

__global__ __launch_bounds__(1024) void scan3_kernel(const int* __restrict__ incl,
                                                     const int* __restrict__ boff,
                                                     int* __restrict__ rp,
                                                     int* __restrict__ cursor) {
    int i = blockIdx.x * SCAN_BLK + threadIdx.x;
    if (i >= N_NODES_C) return;
    int v = incl[i] + boff[blockIdx.x];
    rp[i + 1] = v;
    cursor[i + 1] = v;
    if (i == 0) { rp[0] = 0; cursor[0] = 0; }
}

// ---------------------------------------------------------------------------
// CSR fill: per edge compute scale inline, append (src, scale) to dst bucket
// ---------------------------------------------------------------------------
__global__ void csr_fill_kernel(const int* __restrict__ node_ids,
                                const int* __restrict__ src,
                                const int* __restrict__ dst,
                                const float* __restrict__ ew,
                                const float* __restrict__ alpha,
                                int* __restrict__ cursor,
                                int2* __restrict__ csr) {
    int e = blockIdx.x * blockDim.x + threadIdx.x;
    if (e >= N_EDGES_C) return;
    int s = src[e];
    int d = dst[e];
    int sid = node_ids[s];
    int did = node_ids[d];
    int idx = GENE + 1;                        // cell-cell
    if (sid >= 0 && did < 0) idx = sid;        // gene -> cell
    else if (did >= 0 && sid < 0) idx = did;   // cell -> gene
    else if (sid >= 0 && did >= 0) idx = GENE; // gene -> gene
    float sc = alpha[idx] * ew[e];
    int pos = atomicAdd(&cursor[d], 1);
    csr[pos] = make_int2(s, __float_as_int(sc));
}

// ---------------------------------------------------------------------------
// Aggregation: one wave per node, register accumulation, single write.
// neigh[n] = (1/deg) * sum_{e in in(n)} h[src(e)] * scale(e)
// ---------------------------------------------------------------------------
__global__ __launch_bounds__(256) void aggregate_kernel(
        const float* __restrict__ h,
        const int* __restrict__ rp,
        const int2* __restrict__ csr,
        float* __restrict__ neigh) {
    int node = (blockIdx.x * 256 + threadIdx.x) >> 6;
    int lane = threadIdx.x & 63;
    if (node >= N_NODES_C) return;
    int beg = rp[node];
    int end = rp[node + 1];
    float acc0 = 0.0f, acc1 = 0.0f;
    for (int k = beg; k < end; ++k) {
        int2 pr = csr[k];                      // wave-uniform -> broadcast
        const float* __restrict__ hr = h + (size_t)pr.x * FEATS;
        float w = __int_as_float(pr.y);
        acc0 = fmaf(hr[lane], w, acc0);
        if (lane < FEATS - 64) acc1 = fmaf(hr[lane + 64], w, acc1);
    }
    float invd = (end > beg) ? 1.0f / (float)(end - beg) : 0.0f;
    float* __restrict__ nr = neigh + (size_t)node * FEATS;
    nr[lane] = acc0 * invd;
    if (lane < FEATS - 64) nr[lane + 64] = acc1 * invd;
}

// ---------------------------------------------------------------------------
// Dense layer: thread j owns output column j; W row in VGPRs; 8 input rows
// staged in LDS per barrier round.
// ---------------------------------------------------------------------------
template <int NOUT, bool RELU>
__global__ __launch_bounds__(128) void dense_kernel(
        const float* __restrict__ in,
        const float* __restrict__ W,
        const float* __restrict__ b,
        float* __restrict__ out) {
    __shared__ float rows[8][FEATS];
    const int j = threadIdx.x;

    float w[FEATS];
    float bias = 0.0f;
    if (j < NOUT) {
        bias = b[j];
        #pragma unroll
        for (int k4 = 0; k4 < FEATS / 4; ++k4) {
            float4 v = reinterpret_cast<const float4*>(W + (size_t)j * FEATS)[k4];
            w[4 * k4 + 0] = v.x;
            w[4 * k4 + 1] = v.y;
            w[4 * k4 + 2] = v.z;
            w[4 * k4 + 3] = v.w;
        }
    }

    const int ngroups = N_NODES_C / 8;
    for (int g = blockIdx.x; g < ngroups; g += gridDim.x) {
        const int n0 = g * 8;
        if (j < FEATS) {
            #pragma unroll
            for (int m = 0; m < 8; ++m) {
                rows[m][j] = in[(size_t)(n0 + m) * FEATS + j];
            }
        }
        __syncthreads();
        if (j < NOUT) {
            #pragma unroll
            for (int m = 0; m < 8; ++m) {
                float acc = bias;
                #pragma unroll
                for (int k4 = 0; k4 < FEATS / 4; ++k4) {
                    float4 r = reinterpret_cast<const float4*>(rows[m])[k4];
                    acc += r.x * w[4 * k4 + 0];
                    acc += r.y * w[4 * k4 + 1];
                    acc += r.z * w[4 * k4 + 2];
                    acc += r.w * w[4 * k4 + 3];
                }
                if (RELU) acc = fmaxf(acc, 0.0f);
                out[(size_t)(n0 + m) * NOUT + j] = acc;
            }
        }
        __syncthreads();
    }
}

// ---------------------------------------------------------------------------
extern "C" void kernel_launch(void* const* d_in, const int* in_sizes, int n_in,
                              void* d_out, int out_size, void* d_ws, size_t ws_size,
                              hipStream_t stream) {
    const float* features = (const float*)d_in[0];
    const int*   node_ids = (const int*)d_in[1];
    const int*   src      = (const int*)d_in[2];
    const int*   dst      = (const int*)d_in[3];
    const float* ew       = (const float*)d_in[4];
    const float* alpha    = (const float*)d_in[5];
    const float* W1       = (const float*)d_in[6];
    const float* b1       = (const float*)d_in[7];
    const float* W2       = (const float*)d_in[8];
    const float* b2       = (const float*)d_in[9];
    const float* lin_w    = (const float*)d_in[10];
    const float* lin_b    = (const float*)d_in[11];
    float* out = (float*)d_out;

    char* ws = (char*)d_ws;
    size_t off = 0;
    auto alloc = [&](size_t bytes) {
        void* p = ws + off;
        off += (bytes + 255) & ~(size_t)255;
        return p;
    };
    int*  deg    = (int*)alloc((size_t)N_NODES_C * 4);         // becomes incl scan
    int*  bsum   = (int*)alloc((size_t)SCAN_NBLK * 4);
    int*  rp     = (int*)alloc((size_t)(N_NODES_C + 1) * 4);
    int*  cursor = (int*)alloc((size_t)(N_NODES_C + 1) * 4);
    int2* csr    = (int2*)alloc((size_t)N_EDGES_C * 8);
    float* neigh = (float*)alloc((size_t)N_NODES_C * FEATS * 4);
    float* h     = (float*)alloc((size_t)N_NODES_C * FEATS * 4);
    (void)ws_size;

    // --- CSR build -----------------------------------------------------------
    hipMemsetAsync(deg, 0, (size_t)N_NODES_C * 4, stream);
    deg_count_kernel<<<(N_EDGES_C + 255) / 256, 256, 0, stream>>>(dst, deg);
    scan1_kernel<<<SCAN_NBLK, SCAN_BLK, 0, stream>>>(deg, bsum);
    scan2_kernel<<<1, 128, 0, stream>>>(bsum);
    scan3_kernel<<<SCAN_NBLK, SCAN_BLK, 0, stream>>>(deg, bsum, rp, cursor);
    csr_fill_kernel<<<(N_EDGES_C + 255) / 256, 256, 0, stream>>>(
        node_ids, src, dst, ew, alpha, cursor, csr);

    // --- Layer 1 -------------------------------------------------------------
    aggregate_kernel<<<(N_NODES_C * 64) / 256, 256, 0, stream>>>(features, rp, csr, neigh);
    dense_kernel<FEATS, true><<<2048, 128, 0, stream>>>(neigh, W1, b1, h);

    // --- Layer 2 -------------------------------------------------------------
    aggregate_kernel<<<(N_NODES_C * 64) / 256, 256, 0, stream>>>(h, rp, csr, neigh);
    dense_kernel<FEATS, true><<<2048, 128, 0, stream>>>(neigh, W2, b2, h);

    // --- Classifier ----------------------------------------------------------
    dense_kernel<NCLS, false><<<2048, 128, 0, stream>>>(h, lin_w, lin_b, out);
}